// Round 2
// baseline (495.470 us; speedup 1.0000x reference)
//
#include <hip/hip_runtime.h>
#include <stdint.h>
#include <math.h>

#define BB   4096
#define CC   32000
#define KK   30
#define TPB  256
#define NBIN 8192
#define NWORD (NBIN / 2)
#define SHIFT 19
#define CAP  1024

// Order-preserving float->uint mapping (no NaNs in this data).
__device__ __forceinline__ uint32_t fkey(float f) {
  uint32_t u = __float_as_uint(f);
  return (u & 0x80000000u) ? ~u : (u | 0x80000000u);
}
__device__ __forceinline__ float unfkey(uint32_t k) {
  uint32_t u = (k & 0x80000000u) ? (k & 0x7fffffffu) : ~k;
  return __uint_as_float(u);
}

struct SharedState {
  uint32_t           hist[NWORD];     // 16 KB, 2 x u16 counters per word
  unsigned long long cand[CAP];      // 8 KB candidate (key, ~idx) pairs
  unsigned long long waveBuf[4 * KK];
  uint32_t           segSum[TPB];
  uint32_t           candCnt;
  uint32_t           bstar;
  uint32_t           trueIdx[KK];
  uint32_t           predIdx[KK];
};

// Exact top-30 indices (value desc, ties -> lowest index) of row[0..CC).
__device__ void topk_row(const float* __restrict__ row, SharedState& S,
                         uint32_t* outIdx) {
  const int tid  = threadIdx.x;
  const int lane = tid & 63;
  const int w    = tid >> 6;

  // ---- clear histogram + counter ----
  for (int i = tid; i < NWORD; i += TPB) S.hist[i] = 0;
  if (tid == 0) S.candCnt = 0;
  __syncthreads();

  const float4* row4 = reinterpret_cast<const float4*>(row);

  // ---- pass 1: 13-bit key histogram (packed u16 pairs) ----
  for (int j = tid; j < CC / 4; j += TPB) {
    float4 v = row4[j];
    uint32_t b0 = fkey(v.x) >> SHIFT;
    uint32_t b1 = fkey(v.y) >> SHIFT;
    uint32_t b2 = fkey(v.z) >> SHIFT;
    uint32_t b3 = fkey(v.w) >> SHIFT;
    atomicAdd(&S.hist[b0 >> 1], (b0 & 1) ? 0x10000u : 1u);
    atomicAdd(&S.hist[b1 >> 1], (b1 & 1) ? 0x10000u : 1u);
    atomicAdd(&S.hist[b2 >> 1], (b2 & 1) ? 0x10000u : 1u);
    atomicAdd(&S.hist[b3 >> 1], (b3 & 1) ? 0x10000u : 1u);
  }
  __syncthreads();

  // ---- per-thread segment sums (descending segments of 32 bins) ----
  {
    uint32_t s = 0;
    int base = NWORD - (tid + 1) * (NWORD / TPB);
#pragma unroll
    for (int i = 0; i < NWORD / TPB; ++i) {
      uint32_t h = S.hist[base + i];
      s += (h & 0xffffu) + (h >> 16);
    }
    S.segSum[tid] = s;
  }
  __syncthreads();

  // ---- find bin b* containing the 30th largest ----
  if (tid == 0) {
    uint32_t cum = 0;
    int s = 0;
    for (; s < TPB - 1; ++s) {
      uint32_t t = cum + S.segSum[s];
      if (t >= KK) break;
      cum = t;
    }
    int b    = NBIN - s * 32 - 1;
    int bLow = NBIN - (s + 1) * 32;
    for (;; --b) {
      uint32_t hw = S.hist[b >> 1];
      uint32_t c  = (b & 1) ? (hw >> 16) : (hw & 0xffffu);
      cum += c;
      if (cum >= KK || b == bLow) break;
    }
    S.bstar = (uint32_t)b;
  }
  __syncthreads();

  const float Tf = unfkey(S.bstar << SHIFT);

  // ---- pass 2 (L2/L3-hot): collect all elements with v >= Tf ----
  for (int j = tid; j < CC / 4; j += TPB) {
    float4 v = row4[j];
    if (v.x >= Tf || v.y >= Tf || v.z >= Tf || v.w >= Tf) {
      int b = j << 2;
      if (v.x >= Tf) {
        uint32_t p = atomicAdd(&S.candCnt, 1u);
        if (p < CAP) S.cand[p] =
          ((unsigned long long)fkey(v.x) << 32) | (uint32_t)~(b);
      }
      if (v.y >= Tf) {
        uint32_t p = atomicAdd(&S.candCnt, 1u);
        if (p < CAP) S.cand[p] =
          ((unsigned long long)fkey(v.y) << 32) | (uint32_t)~(b + 1);
      }
      if (v.z >= Tf) {
        uint32_t p = atomicAdd(&S.candCnt, 1u);
        if (p < CAP) S.cand[p] =
          ((unsigned long long)fkey(v.z) << 32) | (uint32_t)~(b + 2);
      }
      if (v.w >= Tf) {
        uint32_t p = atomicAdd(&S.candCnt, 1u);
        if (p < CAP) S.cand[p] =
          ((unsigned long long)fkey(v.w) << 32) | (uint32_t)~(b + 3);
      }
    }
  }
  __syncthreads();

  // ---- per-thread sorted-4 of its strided candidates ----
  unsigned long long k0 = 0, k1 = 0, k2 = 0, k3 = 0;
  uint32_t n = S.candCnt;
  if (n > CAP) n = CAP;
#define SWPK(a, b) { unsigned long long t = k##a; k##a = k##b; k##b = t; }
#pragma unroll
  for (int r = 0; r < 4; ++r) {
    uint32_t p = (uint32_t)tid + r * TPB;
    if (p < n) {
      unsigned long long x = S.cand[p];
      if (x > k3) {
        k3 = x;
        if (k3 > k2) SWPK(3, 2)
        if (k2 > k1) SWPK(2, 1)
        if (k1 > k0) SWPK(1, 0)
      }
    }
  }
#undef SWPK

  // ---- per-wave top-30 via 30 rounds of 64-lane butterfly max ----
  unsigned long long keep = 0ull;
  for (int round = 0; round < KK; ++round) {
    unsigned long long m = k0;
#pragma unroll
    for (int d = 1; d < 64; d <<= 1) {
      unsigned long long o = __shfl_xor(m, d, 64);
      if (o > m) m = o;
    }
    if (k0 == m) { k0 = k1; k1 = k2; k2 = k3; k3 = 0ull; }
    if (lane == round) keep = m;
  }

  __syncthreads();
  if (lane < KK) S.waveBuf[w * KK + lane] = keep;
  __syncthreads();

  // ---- wave 0: merge 4 x 30 candidates -> exact top-30 ----
  if (w == 0) {
    unsigned long long a  = (lane < 2 * KK) ? S.waveBuf[2 * lane]     : 0ull;
    unsigned long long b2 = (lane < 2 * KK) ? S.waveBuf[2 * lane + 1] : 0ull;
    unsigned long long keep2 = 0ull;
    for (int round = 0; round < KK; ++round) {
      unsigned long long m = (a > b2) ? a : b2;
#pragma unroll
      for (int d = 1; d < 64; d <<= 1) {
        unsigned long long o = __shfl_xor(m, d, 64);
        if (o > m) m = o;
      }
      if (a == m)       { a = b2; b2 = 0ull; }
      else if (b2 == m) { b2 = 0ull; }
      if (lane == round) keep2 = m;
    }
    if (lane < KK) outIdx[lane] = ~((uint32_t)(keep2 & 0xffffffffull));
  }
  __syncthreads();
}

__global__ __launch_bounds__(TPB)
void rowloss_kernel(const float* __restrict__ logits,
                    const float* __restrict__ targets,
                    float* __restrict__ ws) {
  const int r   = blockIdx.x;
  const int tid = threadIdx.x;

  __shared__ SharedState S;

  const float* lrow = logits  + (size_t)r * CC;
  const float* trow = targets + (size_t)r * CC;

  topk_row(trow, S, S.trueIdx);   // top-30 of targets
  topk_row(lrow, S, S.predIdx);   // top-30 of logits

  // lanes 0..29 (wave 0): loss terms at true indices + overlap count
  float lossv = 0.f;
  int   ov    = 0;
  if (tid < KK) {
    uint32_t ti = S.trueIdx[tid];
    float x = lrow[ti];                   // gather, L2/L3 hot
    float p = 1.f / (1.f + expf(-x));     // sigmoid, TEMPERATURE = 1
    lossv = -logf(p + 1e-7f);
#pragma unroll
    for (int jj = 0; jj < KK; ++jj) ov += (ti == S.predIdx[jj]) ? 1 : 0;
  }
  if (tid < 64) {
#pragma unroll
    for (int d = 32; d >= 1; d >>= 1) {
      lossv += __shfl_down(lossv, d, 64);
      ov    += __shfl_down(ov,    d, 64);
    }
    if (tid == 0) {
      float loss = lossv / (float)KK;
      float wgt  = 1.f - (float)ov / (float)KK;
      ws[r] = loss * wgt;
    }
  }
}

__global__ __launch_bounds__(TPB)
void reduce_kernel(const float* __restrict__ ws, float* __restrict__ out) {
  __shared__ float part[TPB / 64];
  const int tid = threadIdx.x;
  float s = 0.f;
  for (int i = tid; i < BB; i += TPB) s += ws[i];
#pragma unroll
  for (int d = 32; d >= 1; d >>= 1) s += __shfl_down(s, d, 64);
  if ((tid & 63) == 0) part[tid >> 6] = s;
  __syncthreads();
  if (tid == 0) {
    float t = 0.f;
#pragma unroll
    for (int i = 0; i < TPB / 64; ++i) t += part[i];
    out[0] = t / (float)BB;
  }
}

extern "C" void kernel_launch(void* const* d_in, const int* in_sizes, int n_in,
                              void* d_out, int out_size, void* d_ws, size_t ws_size,
                              hipStream_t stream) {
  const float* logits  = (const float*)d_in[0];
  const float* targets = (const float*)d_in[1];
  float* ws  = (float*)d_ws;       // BB floats of scratch
  float* out = (float*)d_out;

  hipLaunchKernelGGL(rowloss_kernel, dim3(BB), dim3(TPB), 0, stream,
                     logits, targets, ws);
  hipLaunchKernelGGL(reduce_kernel, dim3(1), dim3(TPB), 0, stream, ws, out);
}

// Round 3
// 213.665 us; speedup vs baseline: 2.3189x; 2.3189x over previous
//
#include <hip/hip_runtime.h>
#include <stdint.h>
#include <math.h>

#define BB   4096
#define CC   32000
#define KK   30
#define TPB  256
#define CAP  512

// Static pre-thresholds (exactness NOT dependent on these: in-kernel
// count>=30 check + bisection fallback makes any input correct; these only
// set the fast-path candidate density).
#define T_TGT 0.995f   // targets ~ U(0,1): E[count]=160, sigma~12.6
#define T_LGT 2.5f     // logits ~ N(0,1): E[count]=199, sigma~14

// Order-preserving float->uint mapping (no NaNs in this data).
__device__ __forceinline__ uint32_t fkey(float f) {
  uint32_t u = __float_as_uint(f);
  return (u & 0x80000000u) ? ~u : (u | 0x80000000u);
}
__device__ __forceinline__ float unfkey(uint32_t k) {
  uint32_t u = (k & 0x80000000u) ? (k & 0x7fffffffu) : ~k;
  return __uint_as_float(u);
}

// Rescan fallback (rare): collect {v >= unfkey(Tk)} with companion values.
__device__ uint32_t rescan(const float4* __restrict__ row4,
                           const float4* __restrict__ comp4,
                           uint32_t Tk,
                           unsigned long long* cand, float* comp,
                           uint32_t* cntp, int tid) {
  __syncthreads();
  if (tid == 0) *cntp = 0;
  __syncthreads();
  const float T = unfkey(Tk);
  for (int j = tid; j < CC / 4; j += TPB) {
    float4 v = row4[j];
    if (v.x >= T || v.y >= T || v.z >= T || v.w >= T) {
      float4 c = comp4[j];
      int b = j << 2;
      if (v.x >= T) { uint32_t p = atomicAdd(cntp, 1u); if (p < CAP) {
        cand[p] = ((unsigned long long)fkey(v.x) << 32) | (uint32_t)~b;     comp[p] = c.x; } }
      if (v.y >= T) { uint32_t p = atomicAdd(cntp, 1u); if (p < CAP) {
        cand[p] = ((unsigned long long)fkey(v.y) << 32) | (uint32_t)~(b+1); comp[p] = c.y; } }
      if (v.z >= T) { uint32_t p = atomicAdd(cntp, 1u); if (p < CAP) {
        cand[p] = ((unsigned long long)fkey(v.z) << 32) | (uint32_t)~(b+2); comp[p] = c.z; } }
      if (v.w >= T) { uint32_t p = atomicAdd(cntp, 1u); if (p < CAP) {
        cand[p] = ((unsigned long long)fkey(v.w) << 32) | (uint32_t)~(b+3); comp[p] = c.w; } }
    }
  }
  __syncthreads();
  return *cntp;
}

// Exact top-KK by rank-counting over n (<= CAP) unique keys in LDS.
// Ties (equal value) resolve to lowest index, matching jax.lax.top_k.
__device__ void select_topk(const unsigned long long* cand, const float* compv,
                            uint32_t n, uint32_t* outIdx, float* outComp,
                            int tid) {
  unsigned long long m0 = (tid < (int)n)        ? cand[tid]        : 0ull;
  unsigned long long m1 = (tid + TPB < (int)n)  ? cand[tid + TPB]  : 0ull;
  int r0 = 0, r1 = 0;
#pragma unroll 8
  for (uint32_t j = 0; j < n; ++j) {
    unsigned long long x = cand[j];   // broadcast read, conflict-free
    r0 += (x > m0) ? 1 : 0;
    r1 += (x > m1) ? 1 : 0;
  }
  if (tid < (int)n && r0 < KK) {
    outIdx[r0] = ~((uint32_t)(m0 & 0xffffffffull));
    if (outComp) outComp[r0] = compv[tid];
  }
  if (tid + TPB < (int)n && r1 < KK) {
    outIdx[r1] = ~((uint32_t)(m1 & 0xffffffffull));
    if (outComp) outComp[r1] = compv[tid + TPB];
  }
}

__global__ __launch_bounds__(TPB)
void rowloss_kernel(const float* __restrict__ logits,
                    const float* __restrict__ targets,
                    float* __restrict__ ws) {
  const int r   = blockIdx.x;
  const int tid = threadIdx.x;

  __shared__ unsigned long long candT[CAP];   // target candidates (key,~idx)
  __shared__ unsigned long long candL[CAP];   // logit  candidates
  __shared__ float              compT[CAP];   // logit value at target cand idx
  __shared__ float              compL[CAP];   // (unused companion for logits)
  __shared__ uint32_t cntT, cntL;
  __shared__ uint32_t trueIdx[KK], predIdx[KK];
  __shared__ float    trueLogit[KK];

  const float4* t4 = reinterpret_cast<const float4*>(targets + (size_t)r * CC);
  const float4* l4 = reinterpret_cast<const float4*>(logits  + (size_t)r * CC);

  if (tid == 0) { cntT = 0; cntL = 0; }
  __syncthreads();

  // ---- single fused pass: stream both rows, threshold-filter ----
#pragma unroll 2
  for (int j = tid; j < CC / 4; j += TPB) {
    float4 tv = t4[j];
    float4 lv = l4[j];
    int b = j << 2;
    if (tv.x >= T_TGT) { uint32_t p = atomicAdd(&cntT, 1u); if (p < CAP) {
      candT[p] = ((unsigned long long)fkey(tv.x) << 32) | (uint32_t)~b;     compT[p] = lv.x; } }
    if (tv.y >= T_TGT) { uint32_t p = atomicAdd(&cntT, 1u); if (p < CAP) {
      candT[p] = ((unsigned long long)fkey(tv.y) << 32) | (uint32_t)~(b+1); compT[p] = lv.y; } }
    if (tv.z >= T_TGT) { uint32_t p = atomicAdd(&cntT, 1u); if (p < CAP) {
      candT[p] = ((unsigned long long)fkey(tv.z) << 32) | (uint32_t)~(b+2); compT[p] = lv.z; } }
    if (tv.w >= T_TGT) { uint32_t p = atomicAdd(&cntT, 1u); if (p < CAP) {
      candT[p] = ((unsigned long long)fkey(tv.w) << 32) | (uint32_t)~(b+3); compT[p] = lv.w; } }

    if (lv.x >= T_LGT) { uint32_t p = atomicAdd(&cntL, 1u); if (p < CAP) {
      candL[p] = ((unsigned long long)fkey(lv.x) << 32) | (uint32_t)~b;     } }
    if (lv.y >= T_LGT) { uint32_t p = atomicAdd(&cntL, 1u); if (p < CAP) {
      candL[p] = ((unsigned long long)fkey(lv.y) << 32) | (uint32_t)~(b+1); } }
    if (lv.z >= T_LGT) { uint32_t p = atomicAdd(&cntL, 1u); if (p < CAP) {
      candL[p] = ((unsigned long long)fkey(lv.z) << 32) | (uint32_t)~(b+2); } }
    if (lv.w >= T_LGT) { uint32_t p = atomicAdd(&cntL, 1u); if (p < CAP) {
      candL[p] = ((unsigned long long)fkey(lv.w) << 32) | (uint32_t)~(b+3); } }
  }
  __syncthreads();

  // ---- exactness guard: bisection fallback (never taken on this data) ----
  uint32_t nT = cntT;
  if (nT < KK || nT > CAP) {
    uint32_t lo = 0u, hi = 0xffffffffu, k = fkey(T_TGT);
    for (int it = 0; it < 40 && (nT < KK || nT > CAP); ++it) {
      if (nT < KK) hi = k; else lo = k;
      k = lo + ((hi - lo) >> 1);
      nT = rescan(t4, l4, k, candT, compT, &cntT, tid);
    }
  }
  uint32_t nL = cntL;
  if (nL < KK || nL > CAP) {
    uint32_t lo = 0u, hi = 0xffffffffu, k = fkey(T_LGT);
    for (int it = 0; it < 40 && (nL < KK || nL > CAP); ++it) {
      if (nL < KK) hi = k; else lo = k;
      k = lo + ((hi - lo) >> 1);
      nL = rescan(l4, l4, k, candL, compL, &cntL, tid);
    }
  }
  if (nT > CAP) nT = CAP;
  if (nL > CAP) nL = CAP;

  // ---- exact top-30 of each candidate set ----
  select_topk(candT, compT, nT, trueIdx, trueLogit, tid);
  select_topk(candL, compL, nL, predIdx, (float*)nullptr, tid);
  __syncthreads();

  // ---- loss terms + overlap (lanes 0..29 of wave 0) ----
  float lossv = 0.f;
  int   ov    = 0;
  if (tid < KK) {
    float x = trueLogit[tid];
    float p = 1.f / (1.f + expf(-x));     // sigmoid, TEMPERATURE = 1
    lossv = -logf(p + 1e-7f);
    uint32_t ti = trueIdx[tid];
#pragma unroll
    for (int jj = 0; jj < KK; ++jj) ov += (ti == predIdx[jj]) ? 1 : 0;
  }
  if (tid < 64) {
#pragma unroll
    for (int d = 32; d >= 1; d >>= 1) {
      lossv += __shfl_down(lossv, d, 64);
      ov    += __shfl_down(ov,    d, 64);
    }
    if (tid == 0) {
      float loss = lossv / (float)KK;
      float wgt  = 1.f - (float)ov / (float)KK;
      ws[r] = loss * wgt;
    }
  }
}

__global__ __launch_bounds__(TPB)
void reduce_kernel(const float* __restrict__ ws, float* __restrict__ out) {
  __shared__ float part[TPB / 64];
  const int tid = threadIdx.x;
  float s = 0.f;
  for (int i = tid; i < BB; i += TPB) s += ws[i];
#pragma unroll
  for (int d = 32; d >= 1; d >>= 1) s += __shfl_down(s, d, 64);
  if ((tid & 63) == 0) part[tid >> 6] = s;
  __syncthreads();
  if (tid == 0) {
    float t = 0.f;
#pragma unroll
    for (int i = 0; i < TPB / 64; ++i) t += part[i];
    out[0] = t / (float)BB;
  }
}

extern "C" void kernel_launch(void* const* d_in, const int* in_sizes, int n_in,
                              void* d_out, int out_size, void* d_ws, size_t ws_size,
                              hipStream_t stream) {
  const float* logits  = (const float*)d_in[0];
  const float* targets = (const float*)d_in[1];
  float* ws  = (float*)d_ws;       // BB floats of scratch
  float* out = (float*)d_out;

  hipLaunchKernelGGL(rowloss_kernel, dim3(BB), dim3(TPB), 0, stream,
                     logits, targets, ws);
  hipLaunchKernelGGL(reduce_kernel, dim3(1), dim3(TPB), 0, stream, ws, out);
}

// Round 4
// 194.504 us; speedup vs baseline: 2.5473x; 1.0985x over previous
//
#include <hip/hip_runtime.h>
#include <stdint.h>
#include <math.h>

#define BB   4096
#define CC   32000
#define KK   30
#define TPB  256
#define CAP  512

// Static pre-thresholds (exactness NOT dependent on these: in-kernel
// count>=30 / count<=CAP check + bisection fallback makes any input correct;
// these only set the fast-path candidate density).
#define T_TGT 0.995f   // targets ~ U(0,1): E[count]=160, sigma~12.6
#define T_LGT 2.5f     // logits ~ N(0,1): E[count]=199, sigma~14

typedef float f32x4 __attribute__((ext_vector_type(4)));

// Order-preserving float->uint mapping (no NaNs in this data).
__device__ __forceinline__ uint32_t fkey(float f) {
  uint32_t u = __float_as_uint(f);
  return (u & 0x80000000u) ? ~u : (u | 0x80000000u);
}
__device__ __forceinline__ float unfkey(uint32_t k) {
  uint32_t u = (k & 0x80000000u) ? (k & 0x7fffffffu) : ~k;
  return __uint_as_float(u);
}

// Rescan fallback (rare): collect {v >= unfkey(Tk)} with companion values.
__device__ uint32_t rescan(const f32x4* __restrict__ row4,
                           const f32x4* __restrict__ comp4,
                           uint32_t Tk,
                           unsigned long long* cand, float* comp,
                           uint32_t* cntp, int tid) {
  __syncthreads();
  if (tid == 0) *cntp = 0;
  __syncthreads();
  const float T = unfkey(Tk);
  for (int j = tid; j < CC / 4; j += TPB) {
    f32x4 v = row4[j];
    if (v.x >= T || v.y >= T || v.z >= T || v.w >= T) {
      f32x4 c = comp4[j];
      int b = j << 2;
      if (v.x >= T) { uint32_t p = atomicAdd(cntp, 1u); if (p < CAP) {
        cand[p] = ((unsigned long long)fkey(v.x) << 32) | (uint32_t)~b;     comp[p] = c.x; } }
      if (v.y >= T) { uint32_t p = atomicAdd(cntp, 1u); if (p < CAP) {
        cand[p] = ((unsigned long long)fkey(v.y) << 32) | (uint32_t)~(b+1); comp[p] = c.y; } }
      if (v.z >= T) { uint32_t p = atomicAdd(cntp, 1u); if (p < CAP) {
        cand[p] = ((unsigned long long)fkey(v.z) << 32) | (uint32_t)~(b+2); comp[p] = c.z; } }
      if (v.w >= T) { uint32_t p = atomicAdd(cntp, 1u); if (p < CAP) {
        cand[p] = ((unsigned long long)fkey(v.w) << 32) | (uint32_t)~(b+3); comp[p] = c.w; } }
    }
  }
  __syncthreads();
  return *cntp;
}

// Exact top-KK by rank-counting over n (<= CAP) unique keys in LDS.
// Ties (equal value) resolve to lowest index, matching jax.lax.top_k.
__device__ void select_topk(const unsigned long long* cand, const float* compv,
                            uint32_t n, uint32_t* outIdx, float* outComp,
                            int tid) {
  unsigned long long m0 = (tid < (int)n)        ? cand[tid]        : 0ull;
  unsigned long long m1 = (tid + TPB < (int)n)  ? cand[tid + TPB]  : 0ull;
  int r0 = 0, r1 = 0;
#pragma unroll 8
  for (uint32_t j = 0; j < n; ++j) {
    unsigned long long x = cand[j];   // broadcast read, conflict-free
    r0 += (x > m0) ? 1 : 0;
    r1 += (x > m1) ? 1 : 0;
  }
  if (tid < (int)n && r0 < KK) {
    outIdx[r0] = ~((uint32_t)(m0 & 0xffffffffull));
    if (outComp) outComp[r0] = compv[tid];
  }
  if (tid + TPB < (int)n && r1 < KK) {
    outIdx[r1] = ~((uint32_t)(m1 & 0xffffffffull));
    if (outComp) outComp[r1] = compv[tid + TPB];
  }
}

__global__ __launch_bounds__(TPB)
void rowloss_kernel(const float* __restrict__ logits,
                    const float* __restrict__ targets,
                    float* __restrict__ ws) {
  const int r   = blockIdx.x;
  const int tid = threadIdx.x;

  __shared__ unsigned long long candT[CAP];   // target candidates (key,~idx)
  __shared__ unsigned long long candL[CAP];   // logit  candidates
  __shared__ float              compT[CAP];   // logit value at target cand idx
  __shared__ float              compL[CAP];   // (companion for fallback path)
  __shared__ uint32_t cntT, cntL;
  __shared__ uint32_t trueIdx[KK], predIdx[KK];
  __shared__ float    trueLogit[KK];

  const f32x4* t4 = reinterpret_cast<const f32x4*>(targets + (size_t)r * CC);
  const f32x4* l4 = reinterpret_cast<const f32x4*>(logits  + (size_t)r * CC);

  if (tid == 0) { cntT = 0; cntL = 0; }
  __syncthreads();

  // ---- single fused pass: stream both rows (non-temporal), mask-fold ----
#pragma unroll 4
  for (int j = tid; j < CC / 4; j += TPB) {
    f32x4 tv = __builtin_nontemporal_load(t4 + j);
    f32x4 lv = __builtin_nontemporal_load(l4 + j);
    uint32_t mt = (tv.x >= T_TGT ? 1u : 0u) | (tv.y >= T_TGT ? 2u : 0u) |
                  (tv.z >= T_TGT ? 4u : 0u) | (tv.w >= T_TGT ? 8u : 0u);
    uint32_t ml = (lv.x >= T_LGT ? 1u : 0u) | (lv.y >= T_LGT ? 2u : 0u) |
                  (lv.z >= T_LGT ? 4u : 0u) | (lv.w >= T_LGT ? 8u : 0u);
    if (mt | ml) {                       // single guard for the whole quad-pair
      int b = j << 2;
      if (mt & 1u) { uint32_t p = atomicAdd(&cntT, 1u); if (p < CAP) {
        candT[p] = ((unsigned long long)fkey(tv.x) << 32) | (uint32_t)~b;     compT[p] = lv.x; } }
      if (mt & 2u) { uint32_t p = atomicAdd(&cntT, 1u); if (p < CAP) {
        candT[p] = ((unsigned long long)fkey(tv.y) << 32) | (uint32_t)~(b+1); compT[p] = lv.y; } }
      if (mt & 4u) { uint32_t p = atomicAdd(&cntT, 1u); if (p < CAP) {
        candT[p] = ((unsigned long long)fkey(tv.z) << 32) | (uint32_t)~(b+2); compT[p] = lv.z; } }
      if (mt & 8u) { uint32_t p = atomicAdd(&cntT, 1u); if (p < CAP) {
        candT[p] = ((unsigned long long)fkey(tv.w) << 32) | (uint32_t)~(b+3); compT[p] = lv.w; } }
      if (ml & 1u) { uint32_t p = atomicAdd(&cntL, 1u); if (p < CAP) {
        candL[p] = ((unsigned long long)fkey(lv.x) << 32) | (uint32_t)~b;     } }
      if (ml & 2u) { uint32_t p = atomicAdd(&cntL, 1u); if (p < CAP) {
        candL[p] = ((unsigned long long)fkey(lv.y) << 32) | (uint32_t)~(b+1); } }
      if (ml & 4u) { uint32_t p = atomicAdd(&cntL, 1u); if (p < CAP) {
        candL[p] = ((unsigned long long)fkey(lv.z) << 32) | (uint32_t)~(b+2); } }
      if (ml & 8u) { uint32_t p = atomicAdd(&cntL, 1u); if (p < CAP) {
        candL[p] = ((unsigned long long)fkey(lv.w) << 32) | (uint32_t)~(b+3); } }
    }
  }
  __syncthreads();

  // ---- exactness guard: bisection fallback (never taken on this data) ----
  uint32_t nT = cntT;
  if (nT < KK || nT > CAP) {
    uint32_t lo = 0u, hi = 0xffffffffu, k = fkey(T_TGT);
    for (int it = 0; it < 40 && (nT < KK || nT > CAP); ++it) {
      if (nT < KK) hi = k; else lo = k;
      k = lo + ((hi - lo) >> 1);
      nT = rescan(t4, l4, k, candT, compT, &cntT, tid);
    }
  }
  uint32_t nL = cntL;
  if (nL < KK || nL > CAP) {
    uint32_t lo = 0u, hi = 0xffffffffu, k = fkey(T_LGT);
    for (int it = 0; it < 40 && (nL < KK || nL > CAP); ++it) {
      if (nL < KK) hi = k; else lo = k;
      k = lo + ((hi - lo) >> 1);
      nL = rescan(l4, l4, k, candL, compL, &cntL, tid);
    }
  }
  if (nT > CAP) nT = CAP;
  if (nL > CAP) nL = CAP;

  // ---- exact top-30 of each candidate set ----
  select_topk(candT, compT, nT, trueIdx, trueLogit, tid);
  select_topk(candL, compL, nL, predIdx, (float*)nullptr, tid);
  __syncthreads();

  // ---- loss terms + overlap (lanes 0..29 of wave 0) ----
  float lossv = 0.f;
  int   ov    = 0;
  if (tid < KK) {
    float x = trueLogit[tid];
    float p = 1.f / (1.f + expf(-x));     // sigmoid, TEMPERATURE = 1
    lossv = -logf(p + 1e-7f);
    uint32_t ti = trueIdx[tid];
#pragma unroll
    for (int jj = 0; jj < KK; ++jj) ov += (ti == predIdx[jj]) ? 1 : 0;
  }
  if (tid < 64) {
#pragma unroll
    for (int d = 32; d >= 1; d >>= 1) {
      lossv += __shfl_down(lossv, d, 64);
      ov    += __shfl_down(ov,    d, 64);
    }
    if (tid == 0) {
      float loss = lossv / (float)KK;
      float wgt  = 1.f - (float)ov / (float)KK;
      ws[r] = loss * wgt;
    }
  }
}

__global__ __launch_bounds__(TPB)
void reduce_kernel(const float* __restrict__ ws, float* __restrict__ out) {
  __shared__ float part[TPB / 64];
  const int tid = threadIdx.x;
  float s = 0.f;
  for (int i = tid; i < BB; i += TPB) s += ws[i];
#pragma unroll
  for (int d = 32; d >= 1; d >>= 1) s += __shfl_down(s, d, 64);
  if ((tid & 63) == 0) part[tid >> 6] = s;
  __syncthreads();
  if (tid == 0) {
    float t = 0.f;
#pragma unroll
    for (int i = 0; i < TPB / 64; ++i) t += part[i];
    out[0] = t / (float)BB;
  }
}

extern "C" void kernel_launch(void* const* d_in, const int* in_sizes, int n_in,
                              void* d_out, int out_size, void* d_ws, size_t ws_size,
                              hipStream_t stream) {
  const float* logits  = (const float*)d_in[0];
  const float* targets = (const float*)d_in[1];
  float* ws  = (float*)d_ws;       // BB floats of scratch
  float* out = (float*)d_out;

  hipLaunchKernelGGL(rowloss_kernel, dim3(BB), dim3(TPB), 0, stream,
                     logits, targets, ws);
  hipLaunchKernelGGL(reduce_kernel, dim3(1), dim3(TPB), 0, stream, ws, out);
}